// Round 3
// baseline (99.405 us; speedup 1.0000x reference)
//
#include <hip/hip_runtime.h>
#include <cstddef>

#define SEQLEN 32
#define BATCH  32768
#define POSE   34
#define HDIM   16
#define PREDL  15
#define RS     88   // Xa row stride in shorts (176B: 2-way-bank-free b128 reads)

typedef __attribute__((ext_vector_type(8))) short short8;
typedef __attribute__((ext_vector_type(4))) float f32x4;

__device__ __forceinline__ float sigm(float x) {
    return __builtin_amdgcn_rcpf(1.0f + __expf(-x));
}
__device__ __forceinline__ float tanh_(float x) {
    return fmaf(2.0f, __builtin_amdgcn_rcpf(1.0f + __expf(-2.0f * x)), -1.0f);
}
__device__ __forceinline__ unsigned short f2bf(float f) {
    __bf16 b = (__bf16)f;                       // v_cvt (RTNE), 1 instr
    return __builtin_bit_cast(unsigned short, b);
}
__device__ __forceinline__ unsigned f22bf(float lo, float hi) {
    return (unsigned)f2bf(lo) | ((unsigned)f2bf(hi) << 16);
}

// gates[16b x 64g]: acc[gt] D-layout col(lane&15)=gate-dim, row=(lane>>4)*4+j=batch
__device__ __forceinline__ void gates_mfma_r(const short8 (&w)[4][2],
                                             short8 a0, short8 a1, f32x4 acc[4]) {
    const f32x4 z = {0.f, 0.f, 0.f, 0.f};
#pragma unroll
    for (int gt = 0; gt < 4; ++gt) {
        f32x4 c = __builtin_amdgcn_mfma_f32_16x16x32_bf16(a0, w[gt][0], z, 0, 0, 0);
        acc[gt]  = __builtin_amdgcn_mfma_f32_16x16x32_bf16(a1, w[gt][1], c, 0, 0, 0);
    }
}

__device__ __forceinline__ void cell_pointwise(const f32x4 acc[4], float cst[4], float hv[4]) {
#pragma unroll
    for (int j = 0; j < 4; ++j) {
        float iv = sigm(acc[0][j]);
        float fv = sigm(acc[1][j]);
        float gv = tanh_(acc[2][j]);
        float ov = sigm(acc[3][j]);
        float cn = fmaf(fv, cst[j], iv * gv);
        cst[j] = cn;
        hv[j] = ov * tanh_(cn);
    }
}

// stage one cell's weights: K layout [x:0..34 | bias:34 | pad | h:40..56 | 0:..64]
__device__ __forceinline__ void stage_w(unsigned short (*Wt)[16][64],
                                        const float* __restrict__ Wih,
                                        const float* __restrict__ Whh,
                                        const float* __restrict__ bih,
                                        const float* __restrict__ bhh, int tid) {
    for (int idx = tid; idx < 4096; idx += 256) {
        int k = idx & 63, n = (idx >> 6) & 15, gt = idx >> 10;
        int row = gt * 16 + n;
        float v = 0.f;
        if (k < 34) v = Wih[row * 34 + k];
        else if (k == 34) v = bih[row] + bhh[row];
        else if (k >= 40 && k < 56) v = Whh[row * 16 + (k - 40)];
        Wt[gt][n][k] = f2bf(v);
    }
}

// encoder x staging helpers: 272 float2 per wave (16 batch x 34, pairs)
__device__ __forceinline__ void ld_x(const float2* __restrict__ s2, int lane, float2 (&xb)[5]) {
#pragma unroll
    for (int it = 0; it < 5; ++it) {
        int i2 = lane + 64 * it;
        if (i2 < 272) xb[it] = s2[i2];
    }
}
__device__ __forceinline__ void st_x(unsigned short* Xa, int lane, const float2 (&xb)[5]) {
#pragma unroll
    for (int it = 0; it < 5; ++it) {
        int i2 = lane + 64 * it;
        if (i2 < 272) {
            int b = i2 / 17, k2 = i2 - b * 17;               // k=2*k2 even
            *(unsigned*)&Xa[b * RS + 2 * k2] = f22bf(xb[it].x, xb[it].y);
        }
    }
}

extern "C" __global__ void __launch_bounds__(256, 2) lstm_mfma(
    const float* __restrict__ obs_s,
    const float* __restrict__ eWih, const float* __restrict__ eWhh,
    const float* __restrict__ ebih, const float* __restrict__ ebhh,
    const float* __restrict__ dWih, const float* __restrict__ dWhh,
    const float* __restrict__ dbih, const float* __restrict__ dbhh,
    const float* __restrict__ cWih, const float* __restrict__ cWhh,
    const float* __restrict__ cbih, const float* __restrict__ cbhh,
    const float* __restrict__ fcW,  const float* __restrict__ fcb,
    const float* __restrict__ fccW, const float* __restrict__ fccb,
    const float* __restrict__ mlpW, const float* __restrict__ mlpb,
    const float* __restrict__ embW, const float* __restrict__ embb,
    float* __restrict__ out_s, float* __restrict__ out_cr)
{
    __shared__ unsigned short WtU[3][4][16][64];   // staged once -> regs
    __shared__ unsigned short fcWtU[3][16][32];    // k16 = bias
    __shared__ unsigned short mlpWtU[16][32];
    __shared__ unsigned short fccWtU[16][32];
    __shared__ float embtL[34][4];                 // {embW[k][0],embW[k][1],embb[k],0}
    __shared__ unsigned short XaU[4][2][16 * RS];  // [wave][0=dec,1=cr] A tiles
    __shared__ float2 pbuf[4][16];

    const int tid  = threadIdx.x;
    const int lane = tid & 63;
    const int wv   = tid >> 6;
    const int lo   = lane & 15;
    const int g    = lane >> 4;
    const int wb   = blockIdx.x * 64 + wv * 16;

    // ---------------- one-time staging ----------------
    stage_w(WtU[0], eWih, eWhh, ebih, ebhh, tid);
    stage_w(WtU[1], dWih, dWhh, dbih, dbhh, tid);
    stage_w(WtU[2], cWih, cWhh, cbih, cbhh, tid);
    for (int idx = tid; idx < 1536; idx += 256) {
        int k = idx & 31, n = (idx >> 5) & 15, nt = idx >> 9;
        int np = nt * 16 + n;
        float v = 0.f;
        if (np < 34) { if (k < 16) v = fcW[np * 16 + k]; else if (k == 16) v = fcb[np]; }
        fcWtU[nt][n][k] = f2bf(v);
    }
    for (int idx = tid; idx < 512; idx += 256) {
        int k = idx & 31, n = idx >> 5;
        mlpWtU[n][k] = f2bf(k < 16 ? mlpW[n * 16 + k] : (k == 16 ? mlpb[n] : 0.f));
        float v = 0.f;
        if (n < 2) { if (k < 16) v = fccW[n * 16 + k]; else if (k == 16) v = fccb[n]; }
        fccWtU[n][k] = f2bf(v);
    }
    if (tid < 136) {
        int k = tid >> 2, cp = tid & 3;
        float v = 0.f;
        if (cp == 0) v = embW[2 * k];
        else if (cp == 1) v = embW[2 * k + 1];
        else if (cp == 2) v = embb[k];
        embtL[k][cp] = v;
    }
    // zero Xa tiles; slots k=34 (gate bias) and k=56 (head bias) = bf16(1.0)
    for (int idx = tid; idx < 5632; idx += 256) {
        int r = (idx % 704) % 44;
        ((unsigned*)XaU)[idx] = (r == 17 || r == 28) ? 0x3F80u : 0u;
    }
    __syncthreads();   // only barrier; waves independent afterwards

    unsigned short* XaD = &XaU[wv][0][0];
    unsigned short* XaC = &XaU[wv][1][0];

    // encoder weights -> VGPRs
    short8 wE[4][2];
#pragma unroll
    for (int gt = 0; gt < 4; ++gt) {
        wE[gt][0] = *(const short8*)&WtU[0][gt][lo][8 * g];
        wE[gt][1] = *(const short8*)&WtU[0][gt][lo][32 + 8 * g];
    }

    float cst[4] = {0.f, 0.f, 0.f, 0.f};

    // ---------------- encoder: depth-2 prefetched, 2x unrolled ----------------
    const float2* o2 = (const float2*)obs_s;
#define SRC2(t) (o2 + ((size_t)(t) * BATCH + wb) * 17)
    float2 xbA[5], xbB[5];
    ld_x(SRC2(0), lane, xbA);
    st_x(XaD, lane, xbA);          // x(0)
    ld_x(SRC2(1), lane, xbA);      // t=1 in A
    short8 a0 = *(const short8*)&XaD[lo * RS + 8 * g];
    short8 a1 = *(const short8*)&XaD[lo * RS + 32 + 8 * g];

#define ENC_BODY(T, BUSE, BLOAD)                                              \
    {                                                                         \
        int tl = (T) + 2; if (tl > 31) tl = 31;                               \
        ld_x(SRC2(tl), lane, BLOAD);                                          \
        f32x4 acc[4];                                                         \
        gates_mfma_r(wE, a0, a1, acc);                                        \
        float hv[4];                                                          \
        cell_pointwise(acc, cst, hv);                                         \
        if ((T) < 31) st_x(XaD, lane, BUSE);                                  \
        _Pragma("unroll")                                                     \
        for (int j = 0; j < 4; ++j)                                           \
            XaD[(g * 4 + j) * RS + 40 + lo] = f2bf(hv[j]);                    \
        a0 = *(const short8*)&XaD[lo * RS + 8 * g];                           \
        a1 = *(const short8*)&XaD[lo * RS + 32 + 8 * g];                      \
    }

    for (int tt = 0; tt < 16; ++tt) {
        int t = 2 * tt;
        ENC_BODY(t, xbA, xbB)
        ENC_BODY(t + 1, xbB, xbA)
    }

    // ---------------- decoder weights -> VGPRs; hc = mlp(h) ----------------
    short8 wD[4][2], wC[4][2], wF[3], wM, wFC;
#pragma unroll
    for (int gt = 0; gt < 4; ++gt) {
        wD[gt][0] = *(const short8*)&WtU[1][gt][lo][8 * g];
        wD[gt][1] = *(const short8*)&WtU[1][gt][lo][32 + 8 * g];
        wC[gt][0] = *(const short8*)&WtU[2][gt][lo][8 * g];
        wC[gt][1] = *(const short8*)&WtU[2][gt][lo][32 + 8 * g];
    }
#pragma unroll
    for (int nt = 0; nt < 3; ++nt) wF[nt] = *(const short8*)&fcWtU[nt][lo][8 * g];
    wM  = *(const short8*)&mlpWtU[lo][8 * g];
    wFC = *(const short8*)&fccWtU[lo][8 * g];

    const f32x4 zv = {0.f, 0.f, 0.f, 0.f};
    {
        short8 ahE = *(const short8*)&XaD[lo * RS + 40 + 8 * g];
        f32x4 o = __builtin_amdgcn_mfma_f32_16x16x32_bf16(ahE, wM, zv, 0, 0, 0);
#pragma unroll
        for (int j = 0; j < 4; ++j)
            XaC[(g * 4 + j) * RS + 40 + lo] = f2bf(o[j]);
    }
    float cc[4] = {0.f, 0.f, 0.f, 0.f};

    // ---------------- decoder: 15 steps, crossing & decoder chains interleaved --
    for (int s = 0; s < PREDL; ++s) {
        short8 a0d = *(const short8*)&XaD[lo * RS + 8 * g];
        short8 a1d = *(const short8*)&XaD[lo * RS + 32 + 8 * g];
        short8 a1c = *(const short8*)&XaC[lo * RS + 32 + 8 * g];
        short8 a0c;
        if (s == 0) {
            a0c = a0d;
            if (g == 0) {
                a1c[0] = (short)XaD[lo * RS + 32];
                a1c[1] = (short)XaD[lo * RS + 33];
            }
        } else {
            float2 pv = pbuf[wv][lo];
            union { short8 s8; unsigned u[4]; } pk;
#pragma unroll
            for (int p = 0; p < 4; ++p) {
                int k0 = 8 * g + 2 * p;
                f32x4 e0 = *(const f32x4*)&embtL[k0][0];
                f32x4 e1 = *(const f32x4*)&embtL[k0 + 1][0];
                pk.u[p] = f22bf(fmaf(pv.x, e0[0], fmaf(pv.y, e0[1], e0[2])),
                                fmaf(pv.x, e1[0], fmaf(pv.y, e1[1], e1[2])));
            }
            a0c = pk.s8;
            if (g == 0) {
                unsigned v = f22bf(
                    fmaf(pv.x, embtL[32][0], fmaf(pv.y, embtL[32][1], embtL[32][2])),
                    fmaf(pv.x, embtL[33][0], fmaf(pv.y, embtL[33][1], embtL[33][2])));
                a1c[0] = (short)(v & 0xFFFFu);
                a1c[1] = (short)(v >> 16);
            }
        }

        // both cells' MFMAs issued together (independent), then both pointwise
        f32x4 accc[4], accd[4];
        gates_mfma_r(wC, a0c, a1c, accc);
        gates_mfma_r(wD, a0d, a1d, accd);
        float hcv[4], hv[4];
        cell_pointwise(accc, cc, hcv);
        cell_pointwise(accd, cst, hv);
#pragma unroll
        for (int j = 0; j < 4; ++j) {
            XaC[(g * 4 + j) * RS + 40 + lo] = f2bf(hcv[j]);
            XaD[(g * 4 + j) * RS + 40 + lo] = f2bf(hv[j]);
        }

        short8 ahc = *(const short8*)&XaC[lo * RS + 40 + 8 * g];
        short8 ahd = *(const short8*)&XaD[lo * RS + 40 + 8 * g];

        // z = hc @ fccW.T + fccb via one MFMA (cols 0/1 = z0/z1)
        f32x4 zac = __builtin_amdgcn_mfma_f32_16x16x32_bf16(ahc, wFC, zv, 0, 0, 0);

        // fc head: curr_s -> global out + bf16 feedback into XaD x-region
        float* po = out_s + ((size_t)s * BATCH + wb) * POSE;
#pragma unroll
        for (int nt = 0; nt < 3; ++nt) {
            f32x4 o = __builtin_amdgcn_mfma_f32_16x16x32_bf16(ahd, wF[nt], zv, 0, 0, 0);
            int np = nt * 16 + lo;
            if (np < POSE) {
#pragma unroll
                for (int j = 0; j < 4; ++j) {
                    int b = g * 4 + j;
                    po[(size_t)b * POSE + np] = o[j];
                    XaD[b * RS + np] = f2bf(o[j]);
                }
            }
        }

        // softmax on 2 logits; p needed on lo==0 lanes only
        float zs[4];
#pragma unroll
        for (int j = 0; j < 4; ++j) zs[j] = __shfl_xor(zac[j], 1);
        if (lo == 0) {
            float2* ocr2 = (float2*)out_cr;
#pragma unroll
            for (int j = 0; j < 4; ++j) {
                float z0 = zac[j], z1 = zs[j];
                float mx = fmaxf(z0, z1);
                float e0 = __expf(z0 - mx), e1 = __expf(z1 - mx);
                float rs = __builtin_amdgcn_rcpf(e0 + e1);
                float2 p = make_float2(e0 * rs, e1 * rs);
                int b = g * 4 + j;
                pbuf[wv][b] = p;
                ocr2[(size_t)s * BATCH + wb + b] = p;
            }
        }
    }
}

extern "C" void kernel_launch(void* const* d_in, const int* in_sizes, int n_in,
                              void* d_out, int out_size, void* d_ws, size_t ws_size,
                              hipStream_t stream)
{
    const float* obs  = (const float*)d_in[0];
    const float* eWih = (const float*)d_in[1];
    const float* eWhh = (const float*)d_in[2];
    const float* ebih = (const float*)d_in[3];
    const float* ebhh = (const float*)d_in[4];
    const float* dWih = (const float*)d_in[5];
    const float* dWhh = (const float*)d_in[6];
    const float* dbih = (const float*)d_in[7];
    const float* dbhh = (const float*)d_in[8];
    const float* cWih = (const float*)d_in[9];
    const float* cWhh = (const float*)d_in[10];
    const float* cbih = (const float*)d_in[11];
    const float* cbhh = (const float*)d_in[12];
    const float* fcW  = (const float*)d_in[13];
    const float* fcb  = (const float*)d_in[14];
    const float* fccW = (const float*)d_in[15];
    const float* fccb = (const float*)d_in[16];
    const float* mlpW = (const float*)d_in[17];
    const float* mlpb = (const float*)d_in[18];
    const float* embW = (const float*)d_in[19];
    const float* embb = (const float*)d_in[20];

    float* out_s  = (float*)d_out;
    float* out_cr = out_s + (size_t)PREDL * BATCH * POSE;

    dim3 grid(BATCH / 64), block(256);
    hipLaunchKernelGGL(lstm_mfma, grid, block, 0, stream,
                       obs, eWih, eWhh, ebih, ebhh, dWih, dWhh, dbih, dbhh,
                       cWih, cWhh, cbih, cbhh, fcW, fcb, fccW, fccb,
                       mlpW, mlpb, embW, embb, out_s, out_cr);
}